// Round 4
// baseline (344.864 us; speedup 1.0000x reference)
//
#include <hip/hip_runtime.h>

#define S_SCALE 30.0f
#define COS_M 0.8775825618903728f
#define SIN_M 0.479425538604203f
#define TH_C (-0.8775825618903728f)
#define MM_C 0.2397127693021015f

#define BD 512
#define DD 512
#define CC 100000
#define NCB2 782            // ceil(100000/128)
#define LASTB2 781
#define NPART 1564          // 782 blocks x 2 col-groups of 64

typedef __bf16 bf16x8 __attribute__((ext_vector_type(8)));
typedef float  f32x4  __attribute__((ext_vector_type(4)));

#define AS1 __attribute__((address_space(1)))
#define AS3 __attribute__((address_space(3)))

// ---------------- Kernel 1: concat + normalize -> k-tiled bf16 A_t[16][512][32];
// one WAVE per row, no barriers, fully vectorized. Also label-column cosine/phi. ------
__global__ __launch_bounds__(256) void k_prep(const float* __restrict__ img,
                                              const float* __restrict__ prof,
                                              const float* __restrict__ W,
                                              const int* __restrict__ lab,
                                              __bf16* __restrict__ At,
                                              float* __restrict__ sphi,
                                              float* __restrict__ scos) {
    const int t = threadIdx.x;
    const int wave = t >> 6, l = t & 63;
    const int row = blockIdx.x * 4 + wave;          // 128 blocks x 4 waves = 512 rows
    const float* src = (row < 256) ? (img + (size_t)row * DD) : (prof + (size_t)(row - 256) * DD);
    float4 v0 = ((const float4*)src)[l * 2];
    float4 v1 = ((const float4*)src)[l * 2 + 1];
    float s = v0.x * v0.x + v0.y * v0.y + v0.z * v0.z + v0.w * v0.w
            + v1.x * v1.x + v1.y * v1.y + v1.z * v1.z + v1.w * v1.w;
    #pragma unroll
    for (int o = 1; o < 64; o <<= 1) s += __shfl_xor(s, o);
    float r = rsqrtf(s);
    bf16x8 a;
    a[0] = (__bf16)(v0.x * r); a[1] = (__bf16)(v0.y * r);
    a[2] = (__bf16)(v0.z * r); a[3] = (__bf16)(v0.w * r);
    a[4] = (__bf16)(v1.x * r); a[5] = (__bf16)(v1.y * r);
    a[6] = (__bf16)(v1.z * r); a[7] = (__bf16)(v1.w * r);
    // k-tiled layout: element (row, d) -> At[(d>>5)*16384 + row*32 + (d&31)]
    *(bf16x8*)(At + (size_t)(l >> 2) * (BD * 32) + row * 32 + (l & 3) * 8) = a;

    // label-column cosine (on bf16-truncated values, matching the GEMM)
    const int c = lab[row & 255];
    const float4* wc = (const float4*)(W + (size_t)c * DD);
    float4 w0 = wc[l * 2], w1 = wc[l * 2 + 1];
    float wb0 = (float)(__bf16)w0.x, wb1 = (float)(__bf16)w0.y;
    float wb2 = (float)(__bf16)w0.z, wb3 = (float)(__bf16)w0.w;
    float wb4 = (float)(__bf16)w1.x, wb5 = (float)(__bf16)w1.y;
    float wb6 = (float)(__bf16)w1.z, wb7 = (float)(__bf16)w1.w;
    float dot = (float)a[0] * wb0 + (float)a[1] * wb1 + (float)a[2] * wb2 + (float)a[3] * wb3
              + (float)a[4] * wb4 + (float)a[5] * wb5 + (float)a[6] * wb6 + (float)a[7] * wb7;
    float wsq = wb0 * wb0 + wb1 * wb1 + wb2 * wb2 + wb3 * wb3
              + wb4 * wb4 + wb5 * wb5 + wb6 * wb6 + wb7 * wb7;
    #pragma unroll
    for (int o = 1; o < 64; o <<= 1) { dot += __shfl_xor(dot, o); wsq += __shfl_xor(wsq, o); }
    if (l == 0) {
        float cs = dot * rsqrtf(wsq);
        float sn = sqrtf(fmaxf(0.f, fminf(1.f, 1.f - cs * cs)));
        float phi = cs * COS_M - sn * SIN_M;
        if (!(cs > TH_C)) phi = cs - MM_C;
        sphi[row] = S_SCALE * phi;
        scos[row] = S_SCALE * cs;
    }
}

// ---------------- Kernel 2: MFMA GEMM, 512 rows x 128 cols per 512-thread block ------
// A staged via global_load_lds into a 4-deep LDS ring: tile kt+2 issued at iter kt
// (2 iterations of latency cover). W staged via 4-deep register ring (~3.5 iters).
// Hand-counted vmcnt per fully-unrolled iteration; A/W streams NEVER drained.
// XOR chunk swizzle on glds SOURCE + ds_read addr (LDS linear; conflicts ~0).
__global__ __launch_bounds__(512, 2) void k_gemm(const __bf16* __restrict__ At,
                                                 const float* __restrict__ W,
                                                 float* __restrict__ part) {
    __shared__ __bf16 As[4][BD * 32];    // 4 x 32 KB ring
    __shared__ __bf16 Bs[2][128 * 32];   // 2 x 8 KB
    __shared__ float  csq[128];

    const int t = threadIdx.x;           // 0..511
    const int cb = blockIdx.x;           // 0..781
    const int wave = t >> 6, lane = t & 63, q = lane >> 4, m16 = lane & 15;
    const int rg = wave >> 1;            // row group (x128 rows)
    const int cg = wave & 1;             // col group (x64 cols)

    // fragment read offset (elements): row/col r, k-chunk q -> chunk q ^ ((r>>1)&3)
    const int frag_off = m16 * 32 + ((q ^ ((m16 >> 1) & 3)) << 3);

    // W staging: 4 threads per col; thread covers col t>>2, k-elems (t&3)*8..+7 per tile
    const int wcol = t >> 2, kc = t & 3;
    const int gc = cb * 128 + wcol;
    const float* wp = W + (size_t)(gc < CC ? gc : 0) * DD + kc * 8;
    const int wofs = wcol * 32 + ((kc ^ ((wcol >> 1) & 3)) << 3);

    // glds source pre-swizzle (bytes): row t>>2, chunk (t&3) ^ ((t>>3)&3)
    const int srcswz = ((t >> 2) << 6) + ((((t & 3) ^ ((t >> 3) & 3))) << 4);

    f32x4 acc[8][4] = {};
    float sq = 0.f;
    float4 wva[4], wvb[4];               // W ring: tile n -> slot n&3

#define GLDS_TILE(kt, buf)                                                              \
    {                                                                                   \
        const char* gsrc = (const char*)At + (size_t)(kt) * 32768 + srcswz;             \
        _Pragma("unroll")                                                               \
        for (int c4 = 0; c4 < 4; ++c4) {                                                \
            __builtin_amdgcn_global_load_lds(                                           \
                (AS1 void*)(gsrc + c4 * 8192),                                          \
                (AS3 void*)((char*)(&As[buf][0]) + c4 * 8192 + wave * 1024),            \
                16, 0, 0);                                                              \
        }                                                                               \
    }

#define LOAD_W(n)                                                                       \
    {                                                                                   \
        wva[(n) & 3] = *(const float4*)(wp + (n) * 32);                                 \
        wvb[(n) & 3] = *(const float4*)(wp + (n) * 32 + 4);                             \
    }

#define CVT_BS(buf, va, vb)                                                             \
    {                                                                                   \
        bf16x8 b;                                                                       \
        b[0] = (__bf16)(va).x; b[1] = (__bf16)(va).y;                                   \
        b[2] = (__bf16)(va).z; b[3] = (__bf16)(va).w;                                   \
        b[4] = (__bf16)(vb).x; b[5] = (__bf16)(vb).y;                                   \
        b[6] = (__bf16)(vb).z; b[7] = (__bf16)(vb).w;                                   \
        float f;                                                                        \
        f = (float)b[0]; sq += f * f; f = (float)b[1]; sq += f * f;                     \
        f = (float)b[2]; sq += f * f; f = (float)b[3]; sq += f * f;                     \
        f = (float)b[4]; sq += f * f; f = (float)b[5]; sq += f * f;                     \
        f = (float)b[6]; sq += f * f; f = (float)b[7]; sq += f * f;                     \
        *(bf16x8*)(&Bs[buf][wofs]) = b;                                                 \
    }

#define SB() __builtin_amdgcn_sched_barrier(0)

// Issue order per iter: [glds A(kt+2)] [W(kt+4)] | wait vmcnt(VM) lgkm(0) | barrier |
// compute tile kt | CVT W(kt+1) -> Bs[(kt+1)&1].
// VM = ops issued after A(kt)'s 4 glds, by hand for the full unrolled schedule.
#define ITER(kt, VM)                                                                    \
    {                                                                                   \
        if ((kt) + 2 <= 15) GLDS_TILE((kt) + 2, ((kt) + 2) & 3);                        \
        SB();                                                                           \
        if ((kt) + 4 <= 15) LOAD_W((kt) + 4);                                           \
        SB();                                                                           \
        asm volatile("s_waitcnt vmcnt(" #VM ") lgkmcnt(0)" ::: "memory");               \
        __builtin_amdgcn_s_barrier();                                                   \
        SB();                                                                           \
        bf16x8 bfrag[4];                                                                \
        _Pragma("unroll")                                                               \
        for (int j = 0; j < 4; ++j)                                                     \
            bfrag[j] = *(const bf16x8*)(&Bs[(kt) & 1][cg * 2048 + j * 512 + frag_off]); \
        __builtin_amdgcn_s_setprio(1);                                                  \
        _Pragma("unroll")                                                               \
        for (int i = 0; i < 8; ++i) {                                                   \
            bf16x8 afrag =                                                              \
                *(const bf16x8*)(&As[(kt) & 3][rg * 4096 + i * 512 + frag_off]);        \
            _Pragma("unroll")                                                           \
            for (int j = 0; j < 4; ++j)                                                 \
                acc[i][j] = __builtin_amdgcn_mfma_f32_16x16x32_bf16(                    \
                    afrag, bfrag[j], acc[i][j], 0, 0, 0);                               \
        }                                                                               \
        __builtin_amdgcn_s_setprio(0);                                                  \
        SB();                                                                           \
        if ((kt) + 1 <= 15) CVT_BS(((kt) + 1) & 1, wva[((kt) + 1) & 3],                 \
                                   wvb[((kt) + 1) & 3]);                                \
    }

    // ---- prologue (pinned order): W(0),W(1) | A(0),A(1) glds | W(2),W(3) | CVT Bs[0]
    LOAD_W(0); LOAD_W(1);
    SB();
    GLDS_TILE(0, 0); GLDS_TILE(1, 1);
    SB();
    LOAD_W(2); LOAD_W(3);
    SB();
    CVT_BS(0, wva[0], wvb[0]);           // compiler inserts counted wait for W(0) regs

    // vmcnt bookkeeping (ops after A(kt)):
    // kt0: A1(4)+W2,3(4)+A2(4)+W4(2)=14 ; kt1: W2,3(4)+[A2,W4](6)+[A3,W5](6)=16
    // kt2..11: W(kt+2)(2)+6+6=14 ; kt12: 12 ; kt13: 10 ; kt14: 4 ; kt15: 0
    ITER(0, 14);  ITER(1, 16);
    ITER(2, 14);  ITER(3, 14);  ITER(4, 14);  ITER(5, 14);
    ITER(6, 14);  ITER(7, 14);  ITER(8, 14);  ITER(9, 14);
    ITER(10, 14); ITER(11, 14);
    ITER(12, 12); ITER(13, 10); ITER(14, 4);  ITER(15, 0);

    // column sumsq -> csq[128] (4 threads per col: lanes kc=0..3 adjacent)
    sq += __shfl_xor(sq, 1);
    sq += __shfl_xor(sq, 2);
    if (kc == 0) csq[wcol] = sq;
    __syncthreads();

    // epilogue: partial sum of exp(S * cosine) per row, per 64-col group
    const bool lastb = (cb == LASTB2);
    float inv[4]; bool val[4];
    #pragma unroll
    for (int j = 0; j < 4; ++j) {
        int ct = cg * 64 + j * 16 + m16;
        val[j] = (!lastb) || (ct < 32);   // last block: 32 valid cols (group 0, j<2)
        inv[j] = rsqrtf(csq[ct]) * S_SCALE;
    }
    #pragma unroll
    for (int i = 0; i < 8; ++i) {
        #pragma unroll
        for (int r = 0; r < 4; ++r) {
            float e = 0.f;
            #pragma unroll
            for (int j = 0; j < 4; ++j)
                if (val[j]) e += __expf(acc[i][j][r] * inv[j]);
            e += __shfl_xor(e, 1);
            e += __shfl_xor(e, 2);
            e += __shfl_xor(e, 4);
            e += __shfl_xor(e, 8);
            if (m16 == 0)
                part[((size_t)cb * 2 + cg) * BD + rg * 128 + i * 16 + q * 4 + r] = e;
        }
    }
#undef GLDS_TILE
#undef LOAD_W
#undef CVT_BS
#undef SB
#undef ITER
}

// ---------------- Kernel 3a: parallel partial row-sums over column blocks ----------------
__global__ __launch_bounds__(256) void k_reduce1(const float* __restrict__ part,
                                                 float* __restrict__ rowpart) {
    const int b = blockIdx.x;
    const int rg = b >> 5, cp = b & 31;
    const int t = threadIdx.x;
    const int rl = t & 63, ph = t >> 6;     // 4 phases
    const int r0 = rg * 64;
    float s = 0.f;
    for (int c0 = cp * 4 + ph; c0 < NPART; c0 += 128)
        s += part[(size_t)c0 * BD + r0 + rl];
    __shared__ float buf[256];
    buf[t] = s;
    __syncthreads();
    if (t < 64)
        rowpart[(size_t)cp * BD + r0 + t] = buf[t] + buf[t + 64] + buf[t + 128] + buf[t + 192];
}

// ---------------- Kernel 3b: final logsumexp + label correction + mean (1 block) --------
__global__ __launch_bounds__(256) void k_final(const float* __restrict__ rowpart,
                                               const float* __restrict__ sphi,
                                               const float* __restrict__ scos,
                                               float* __restrict__ out) {
    const int t = threadIdx.x;
    float a = 0.f;
    for (int r = t; r < BD; r += 256) {
        float total = 0.f;
        #pragma unroll
        for (int cp = 0; cp < 32; ++cp)
            total += rowpart[(size_t)cp * BD + r];
        float lse = logf(total);
        float sp = sphi[r], sc = scos[r];
        float corr = log1pf(__expf(sp - lse) - __expf(sc - lse));
        a += lse + corr - sp;
    }
    for (int o = 1; o < 64; o <<= 1) a += __shfl_xor(a, o);
    __shared__ float wsum[4];
    if ((t & 63) == 0) wsum[t >> 6] = a;
    __syncthreads();
    if (t == 0) out[0] = (wsum[0] + wsum[1] + wsum[2] + wsum[3]) * (1.0f / 512.0f);
}

extern "C" void kernel_launch(void* const* d_in, const int* in_sizes, int n_in,
                              void* d_out, int out_size, void* d_ws, size_t ws_size,
                              hipStream_t stream) {
    const float* img  = (const float*)d_in[0];
    const float* prof = (const float*)d_in[1];
    const float* W    = (const float*)d_in[2];
    const int*   lab  = (const int*)d_in[3];

    char* ws = (char*)d_ws;
    __bf16* At     = (__bf16*)ws;                  // 512*512*2 = 524288 B (k-tiled)
    float* sphi    = (float*)(ws + 524288);        // 2048 B
    float* scos    = (float*)(ws + 526336);        // 2048 B
    float* part    = (float*)(ws + 528384);        // 1564*512*4 = 3,203,072 B
    float* rowpart = (float*)(ws + 3731456);       // 32*512*4 = 65,536 B

    k_prep<<<128, 256, 0, stream>>>(img, prof, W, lab, At, sphi, scos);
    k_gemm<<<NCB2, 512, 0, stream>>>(At, W, part);
    k_reduce1<<<256, 256, 0, stream>>>(part, rowpart);
    k_final<<<1, 256, 0, stream>>>(rowpart, sphi, scos, (float*)d_out);
}